// Round 10
// baseline (25.679 us; speedup 1.0000x reference)
//
#include <hip/hip_runtime.h>
#include <hip/hip_bf16.h>

#define B_SZ   256
#define N_IN   128
#define F_IN   64
#define G_SZ   128
#define F_OUT  64
#define S_SZ   16
#define K_TOT  1024   // S_SZ * F_IN

#define M_TILE 128
#define BK     64
#define NSTEP  16     // K_TOT / BK
#define THREADS 512   // 8 waves: wave grid 4 (M) x 2 (N)

#define WSTRIDE 72    // W LDS pad: 144 B rows -> 2-way (free) on b128 frag reads

typedef __attribute__((ext_vector_type(8))) short short8;  // 8 bf16
typedef __attribute__((ext_vector_type(4))) float f32x4;
typedef unsigned short u16;
typedef unsigned int   u32;

#define XN (B_SZ * N_IN * F_IN)   // 2,097,152 x elements (4 MB as bf16)

static __device__ __forceinline__ u32 packbf2(float a, float b) {
    // low 16 = a, high 16 = b (RNE); compiler emits v_cvt_pk_bf16_f32
    __hip_bfloat162 h = __float22bfloat162_rn(make_float2(a, b));
    union { __hip_bfloat162 h; u32 u; } c; c.h = h;
    return c.u;
}

// ---- pass 1: x fp32 -> bf16 (same [B][N][F] layout) ----
__global__ __launch_bounds__(256)
void convert_x_kernel(const float* __restrict__ x, u16* __restrict__ xbf) {
    const int i = blockIdx.x * 256 + threadIdx.x;   // 8 floats/thread, exact
    const float4 v0 = reinterpret_cast<const float4*>(x)[i * 2];
    const float4 v1 = reinterpret_cast<const float4*>(x)[i * 2 + 1];
    uint4 p;
    p.x = packbf2(v0.x, v0.y); p.y = packbf2(v0.z, v0.w);
    p.z = packbf2(v1.x, v1.y); p.w = packbf2(v1.z, v1.w);
    reinterpret_cast<uint4*>(xbf)[i] = p;
}

// ---- pass 2: grouped GEMM ----
// A: [128][64] bf16 LINEAR LDS (16 KB), triple-buffered, staged by
// global_load_lds; content XOR-swizzled via the SOURCE address (rule 21).
// W: fp32 reg-staged depth-2 + cvt_pk into padded LDS, double-buffered.
// Sync ledger (explicit, not compiler-assumed):
//  - STAGEA ends with an asm memory fence: A-DMAs issue BEFORE this
//    iteration's W loads.
//  - Barrier waits vmcnt(4) lgkmcnt(0): only the 4 newest VMEM ops
//    (A(t+2)x2 + W(t+2)x2) may remain in flight, so A(t+1) is provably
//    retired before any wave enters the iteration that reads it.
//    Loads for t+2 still roll across the barrier (never vmcnt(0)).
__global__ __launch_bounds__(THREADS)
void sparse_linear_kernel(const u16*   __restrict__ xbf,
                          const int*   __restrict__ idx,
                          const float* __restrict__ W,
                          const float* __restrict__ bias,
                          float*       __restrict__ out)
{
    __shared__ u16 Alds[3][M_TILE * 64];        // 3 x 16 KB, linear
    __shared__ u16 Wlds[2][F_OUT * WSTRIDE];    // 2 x 9 KB, padded

    const int blk   = blockIdx.x;
    const int g     = blk & 127;   // blk, blk+128 share W[g]; 128%8==0 -> same XCD
    const int mt    = blk >> 7;
    const int bbase = mt * M_TILE;

    const int tid  = threadIdx.x;
    const int wave = tid >> 6;
    const int lane = tid & 63;
    const int wr   = wave >> 1;    // 0..3 (M, 32 rows)
    const int wc   = wave & 1;     // 0..1 (N, 32 cols)
    const int lmod = lane & 15;
    const int ldiv = lane >> 4;

    // ---- A staging coords: 2 chunks, id = tid + i*512 in 0..1023 ----
    // m = id>>3 (0..127), slot = id&7 (16B slot); source col pre-swizzled.
    const u16* arow[2]; int adst[2];
    #pragma unroll
    for (int i = 0; i < 2; ++i) {
        int id   = tid + i * THREADS;
        int m    = id >> 3;
        int slot = id & 7;
        arow[i] = xbf + ((size_t)(bbase + m) << 13)            // *8192 (=128*64)
                      + (((slot * 16) ^ ((m & 7) << 4)) >> 1); // swizzled col (elems)
        adst[i] = id * 8;                                      // LDS elem offset
    }

    // ---- W staging coords: 2 chunks ----
    const float* wptr[2]; int lofsW[2];
    #pragma unroll
    for (int i = 0; i < 2; ++i) {
        int id = tid + i * THREADS;
        int o  = id >> 4;                  // 0..63
        int f  = (id & 15) << 2;           // float col
        wptr[i]  = W + (size_t)g * (F_OUT * K_TOT) + (size_t)o * K_TOT + f;
        lofsW[i] = o * (WSTRIDE * 2) + f * 2;
    }

    int rows[NSTEP];
    #pragma unroll
    for (int s = 0; s < NSTEP; ++s) rows[s] = idx[g * S_SZ + s];  // uniform -> SGPR

    f32x4  acc[2][2] = {};
    float4 rw[2][2];                       // W depth-2 register sets

    // A stage for K-step t into Alds[buf]; trailing fence pins DMA issue
    // BEFORE any later VMEM in this iteration (ledger anchor).
    #define STAGEA(t, buf)                                                     \
        {                                                                      \
            _Pragma("unroll")                                                  \
            for (int i = 0; i < 2; ++i) {                                      \
                const u16* gp = arow[i] + (rows[t] << 6);                      \
                __builtin_amdgcn_global_load_lds(                              \
                    (const __attribute__((address_space(1))) void*)gp,         \
                    (__attribute__((address_space(3))) void*)                  \
                        (&Alds[buf][adst[i]]),                                 \
                    16, 0, 0);                                                 \
            }                                                                  \
            asm volatile("" ::: "memory");                                     \
        }

    #define LOADW(t, s)                                                        \
        {                                                                      \
            _Pragma("unroll")                                                  \
            for (int i = 0; i < 2; ++i)                                        \
                rw[s][i] = *reinterpret_cast<const float4*>(wptr[i] + (t) * BK); \
        }

    #define STOREW(s, buf)                                                     \
        {                                                                      \
            _Pragma("unroll")                                                  \
            for (int i = 0; i < 2; ++i) {                                      \
                uint2 p;                                                       \
                p.x = packbf2(rw[s][i].x, rw[s][i].y);                         \
                p.y = packbf2(rw[s][i].z, rw[s][i].w);                         \
                *reinterpret_cast<uint2*>(                                     \
                    reinterpret_cast<char*>(Wlds[buf]) + lofsW[i]) = p;        \
            }                                                                  \
        }

    #define COMPUTE(abuf, wbuf)                                                \
        {                                                                      \
            _Pragma("unroll")                                                  \
            for (int ks = 0; ks < 2; ++ks) {                                   \
                const int kb2 = ks * 64 + ldiv * 16;   /* frag byte col */     \
                short8 a[2], bfr[2];                                           \
                _Pragma("unroll")                                              \
                for (int mi = 0; mi < 2; ++mi) {                               \
                    const int r = wr * 32 + mi * 16 + lmod;                    \
                    a[mi] = *reinterpret_cast<const short8*>(                  \
                        reinterpret_cast<const char*>(Alds[abuf]) +            \
                        r * 128 + (kb2 ^ ((r & 7) << 4)));                     \
                }                                                              \
                _Pragma("unroll")                                              \
                for (int ni = 0; ni < 2; ++ni)                                 \
                    bfr[ni] = *reinterpret_cast<const short8*>(                \
                        reinterpret_cast<const char*>(Wlds[wbuf]) +            \
                        (wc * 32 + ni * 16 + lmod) * (WSTRIDE * 2) + kb2);     \
                _Pragma("unroll")                                              \
                for (int mi = 0; mi < 2; ++mi)                                 \
                    _Pragma("unroll")                                          \
                    for (int ni = 0; ni < 2; ++ni)                             \
                        acc[mi][ni] = __builtin_amdgcn_mfma_f32_16x16x32_bf16( \
                            a[mi], bfr[ni], acc[mi][ni], 0, 0, 0);             \
            }                                                                  \
        }

    // Counted barrier: retire everything older than the t+2 prefetch
    // (A(t+1) DMAs included), keep the 4 newest VMEM ops in flight.
    #define ROLL_BARRIER()                                                     \
        {                                                                      \
            asm volatile("s_waitcnt vmcnt(4) lgkmcnt(0)" ::: "memory");        \
            __builtin_amdgcn_s_barrier();                                      \
            asm volatile("" ::: "memory");                                     \
        }

    // ---- prologue ----
    STAGEA(0, 0);            // A0 in flight (fence: before everything below)
    STAGEA(1, 1);            // A1 in flight
    LOADW(0, 0);
    LOADW(1, 1);
    STOREW(0, 0);            // waits W0 -> A0,A1 (older) retired too
    ROLL_BARRIER();          // outstanding <= W1 (2 ops); Alds[0]/Wlds[0] ready

    // ---- main loop: A triple-buffer (t%3), W double (t&1), rolling vmcnt ----
    #pragma unroll
    for (int t = 0; t < NSTEP; ++t) {
        if (t + 2 < NSTEP) {
            STAGEA(t + 2, (t + 2) % 3);                 // issue-only, fenced first
            LOADW(t + 2, t & 1);                        // issue-only
        }
        COMPUTE(t % 3, t & 1);
        if (t + 1 < NSTEP) {
            STOREW((t + 1) & 1, (t + 1) & 1);           // waits W(t+1) regs
            ROLL_BARRIER();                             // vmcnt(4): A(t+1) retired
        }
    }

    // ---- epilogue: C frag col = lane&15, row = (lane>>4)*4 + r ----
    const int rowbase = bbase + wr * 32 + (ldiv << 2);
    #pragma unroll
    for (int ni = 0; ni < 2; ++ni) {
        const int o  = wc * 32 + ni * 16 + lmod;
        const float bv = bias[g * F_OUT + o];
        #pragma unroll
        for (int mi = 0; mi < 2; ++mi) {
            #pragma unroll
            for (int r = 0; r < 4; ++r) {
                const int brow = rowbase + mi * 16 + r;
                out[(size_t)brow * (G_SZ * F_OUT) + g * F_OUT + o] = acc[mi][ni][r] + bv;
            }
        }
    }
}

// ---- fallback (ws too small; not expected to run) ----
__global__ __launch_bounds__(256)
void naive_kernel(const float* __restrict__ x, const int* __restrict__ idx,
                  const float* __restrict__ W, const float* __restrict__ bias,
                  float* __restrict__ out) {
    const int i = blockIdx.x * 256 + threadIdx.x;   // (b, g, o)
    const int o = i & 63, gg = (i >> 6) & 127, b = i >> 13;
    float s = bias[gg * F_OUT + o];
    for (int t = 0; t < S_SZ; ++t) {
        const int r = idx[gg * S_SZ + t];
        #pragma unroll 8
        for (int f = 0; f < F_IN; ++f)
            s += x[(size_t)b * (N_IN * F_IN) + r * F_IN + f]
               * W[(size_t)gg * (F_OUT * K_TOT) + (size_t)o * K_TOT + t * F_IN + f];
    }
    out[i] = s;
}

extern "C" void kernel_launch(void* const* d_in, const int* in_sizes, int n_in,
                              void* d_out, int out_size, void* d_ws, size_t ws_size,
                              hipStream_t stream) {
    const float* x    = (const float*)d_in[0];
    const int*   idx  = (const int*)d_in[1];
    const float* W    = (const float*)d_in[2];
    const float* bias = (const float*)d_in[3];
    float*       out  = (float*)d_out;

    const size_t need = (size_t)XN * sizeof(u16);   // 4 MB
    if (ws_size >= need) {
        u16* xbf = (u16*)d_ws;
        convert_x_kernel<<<dim3(XN / 8 / 256), dim3(256), 0, stream>>>(x, xbf);
        sparse_linear_kernel<<<dim3(G_SZ * (B_SZ / M_TILE)), dim3(THREADS), 0, stream>>>(
            xbf, idx, W, bias, out);
    } else {
        naive_kernel<<<dim3((B_SZ * G_SZ * F_OUT) / 256), dim3(256), 0, stream>>>(
            x, idx, W, bias, out);
    }
}